// Round 1
// baseline (158.167 us; speedup 1.0000x reference)
//
#include <hip/hip_runtime.h>
#include <math.h>

// Problem: B=8, N=1024, D=128.
// kv[b,n,512] = [k_mu | v_mu | k_sigma | v_sigma] (offsets 0,128,256,384)
// S_mu[b,i,j] = k_mu[b,i,:].v_mu[b,j,:]; S_sg likewise.
// actions_mean[b,i,c] = sum_j unit(pos_i-pos_j)_c * S_mu[b,i,j]
// actions_log_std raw likewise, then clip/exp/tanh-normal tail.

#define NTOK 1024
#define DHEAD 128
#define LSTRIDE 68   // 64 + 4 pad, keeps float4 alignment, <=2-way read conflicts

// partial layout: [js(4)][b(8)][i(1024)][6] floats (amx,amy,amz,alx,aly,alz)

__global__ __launch_bounds__(256, 2) void actor_gemm_kernel(
    const float* __restrict__ kv, const float* __restrict__ pos,
    float* __restrict__ partial)
{
    // LDS: Amu[64][68], Asg[64][68], BmuT[68 rows k][64 j] (as [64][68]), BsgT, PosI[192], PosJ[192]
    __shared__ float lds[4 * 64 * LSTRIDE + 192 + 192];
    float* Amu  = lds;
    float* Asg  = lds + 4352;
    float* BmuT = lds + 8704;
    float* BsgT = lds + 13056;
    float* PosI = lds + 17408;
    float* PosJ = lds + 17600;

    const int t  = threadIdx.x;
    const int tx = t & 15;       // j group
    const int ty = t >> 4;       // i group
    const int b  = blockIdx.z;
    const int i0 = blockIdx.y * 64;
    const int jbase = blockIdx.x * 256;   // 4 j-tiles of 64

    const float* kvb  = kv  + (size_t)b * NTOK * 512;
    const float* posb = pos + (size_t)b * NTOK * 3;

    if (t < 192) PosI[t] = posb[i0 * 3 + t];

    float am[4][3] = {};
    float al[4][3] = {};

    for (int jt = 0; jt < 4; ++jt) {
        const int j0 = jbase + jt * 64;
        float accm[4][4] = {};
        float accs[4][4] = {};

        for (int kc = 0; kc < 2; ++kc) {
            __syncthreads();
            // ---- stage A (i-major) and B (k-major, transposed) chunks ----
            const int kofs = kc * 64;
            #pragma unroll
            for (int rep = 0; rep < 4; ++rep) {
                const int idx = t + rep * 256;       // 0..1023
                const int r   = idx >> 4;            // row 0..63
                const int c4  = (idx & 15) * 4;      // col 0..60
                const float4 vmu = *(const float4*)&kvb[(i0 + r) * 512 +   0 + kofs + c4];
                const float4 vsg = *(const float4*)&kvb[(i0 + r) * 512 + 256 + kofs + c4];
                *(float4*)&Amu[r * LSTRIDE + c4] = vmu;
                *(float4*)&Asg[r * LSTRIDE + c4] = vsg;
                const float4 bmu = *(const float4*)&kvb[(j0 + r) * 512 + 128 + kofs + c4];
                const float4 bsg = *(const float4*)&kvb[(j0 + r) * 512 + 384 + kofs + c4];
                BmuT[(c4 + 0) * LSTRIDE + r] = bmu.x;
                BmuT[(c4 + 1) * LSTRIDE + r] = bmu.y;
                BmuT[(c4 + 2) * LSTRIDE + r] = bmu.z;
                BmuT[(c4 + 3) * LSTRIDE + r] = bmu.w;
                BsgT[(c4 + 0) * LSTRIDE + r] = bsg.x;
                BsgT[(c4 + 1) * LSTRIDE + r] = bsg.y;
                BsgT[(c4 + 2) * LSTRIDE + r] = bsg.z;
                BsgT[(c4 + 3) * LSTRIDE + r] = bsg.w;
            }
            if (kc == 0 && t < 192) PosJ[t] = posb[j0 * 3 + t];
            __syncthreads();

            // ---- compute 64 K-steps ----
            #pragma unroll 2
            for (int k4 = 0; k4 < 16; ++k4) {
                float a_mu[4][4], a_sg[4][4], b_mu[4][4], b_sg[4][4];
                #pragma unroll
                for (int r = 0; r < 4; ++r) {
                    float4 v = *(const float4*)&Amu[(ty * 4 + r) * LSTRIDE + k4 * 4];
                    a_mu[r][0] = v.x; a_mu[r][1] = v.y; a_mu[r][2] = v.z; a_mu[r][3] = v.w;
                    float4 w = *(const float4*)&Asg[(ty * 4 + r) * LSTRIDE + k4 * 4];
                    a_sg[r][0] = w.x; a_sg[r][1] = w.y; a_sg[r][2] = w.z; a_sg[r][3] = w.w;
                }
                #pragma unroll
                for (int q = 0; q < 4; ++q) {
                    float4 v = *(const float4*)&BmuT[(k4 * 4 + q) * LSTRIDE + tx * 4];
                    b_mu[q][0] = v.x; b_mu[q][1] = v.y; b_mu[q][2] = v.z; b_mu[q][3] = v.w;
                    float4 w = *(const float4*)&BsgT[(k4 * 4 + q) * LSTRIDE + tx * 4];
                    b_sg[q][0] = w.x; b_sg[q][1] = w.y; b_sg[q][2] = w.z; b_sg[q][3] = w.w;
                }
                #pragma unroll
                for (int q = 0; q < 4; ++q)
                    #pragma unroll
                    for (int i = 0; i < 4; ++i)
                        #pragma unroll
                        for (int j = 0; j < 4; ++j) {
                            accm[i][j] = fmaf(a_mu[i][q], b_mu[q][j], accm[i][j]);
                            accs[i][j] = fmaf(a_sg[i][q], b_sg[q][j], accs[i][j]);
                        }
            }
        }

        // ---- geometric epilogue: fold S tile into per-i action accumulators ----
        #pragma unroll
        for (int i = 0; i < 4; ++i) {
            const float pix = PosI[(ty * 4 + i) * 3 + 0];
            const float piy = PosI[(ty * 4 + i) * 3 + 1];
            const float piz = PosI[(ty * 4 + i) * 3 + 2];
            #pragma unroll
            for (int j = 0; j < 4; ++j) {
                const float dx = pix - PosJ[(tx * 4 + j) * 3 + 0];
                const float dy = piy - PosJ[(tx * 4 + j) * 3 + 1];
                const float dz = piz - PosJ[(tx * 4 + j) * 3 + 2];
                const float d2 = dx * dx + dy * dy + dz * dz;
                const float inv = d2 > 0.f ? rsqrtf(d2) : 0.f;  // ref adds 1e-8 to norm; negligible, and i==j -> 0
                const float wm = accm[i][j] * inv;
                const float ws = accs[i][j] * inv;
                am[i][0] = fmaf(dx, wm, am[i][0]);
                am[i][1] = fmaf(dy, wm, am[i][1]);
                am[i][2] = fmaf(dz, wm, am[i][2]);
                al[i][0] = fmaf(dx, ws, al[i][0]);
                al[i][1] = fmaf(dy, ws, al[i][1]);
                al[i][2] = fmaf(dz, ws, al[i][2]);
            }
        }
    }

    // ---- reduce over tx (16 lanes) via butterfly shuffles ----
    #pragma unroll
    for (int i = 0; i < 4; ++i)
        #pragma unroll
        for (int c = 0; c < 3; ++c) {
            float vm = am[i][c];
            float vl = al[i][c];
            #pragma unroll
            for (int m = 1; m < 16; m <<= 1) {
                vm += __shfl_xor(vm, m, 64);
                vl += __shfl_xor(vl, m, 64);
            }
            am[i][c] = vm;
            al[i][c] = vl;
        }

    if (tx == 0) {
        const size_t base = (((size_t)blockIdx.x * 8 + b) * NTOK + i0 + ty * 4);
        #pragma unroll
        for (int i = 0; i < 4; ++i) {
            float* p = partial + (base + i) * 6;
            p[0] = am[i][0]; p[1] = am[i][1]; p[2] = am[i][2];
            p[3] = al[i][0]; p[4] = al[i][1]; p[5] = al[i][2];
        }
    }
}

__device__ __forceinline__ float softplusf(float z) {
    return z > 20.f ? z : log1pf(expf(z));
}

__global__ __launch_bounds__(256) void actor_tail_kernel(
    const float* __restrict__ partial, const float* __restrict__ eps,
    float* __restrict__ out)
{
    const int blk = blockIdx.x;            // 0..31
    const int b   = blk >> 2;
    const int i   = (blk & 3) * 256 + threadIdx.x;
    const int gi  = b * NTOK + i;

    float am[3] = {}, al[3] = {};
    #pragma unroll
    for (int js = 0; js < 4; ++js) {
        const float* p = partial + (((size_t)js * 8 + b) * NTOK + i) * 6;
        am[0] += p[0]; am[1] += p[1]; am[2] += p[2];
        al[0] += p[3]; al[1] += p[4]; al[2] += p[5];
    }

    float lp = 0.f;
    #pragma unroll
    for (int c = 0; c < 3; ++c) {
        const float als = fminf(fmaxf(al[c], -20.f), 2.f);
        const float sd  = expf(als);
        const float e   = eps[gi * 3 + c];
        const float pre = fmaf(sd, e, am[c]);
        out[gi * 3 + c] = tanhf(pre) * 0.01f;
        const float t2 = 2.f * pre;
        // normal_lp - log_det, with (pre-mean)/std == eps
        lp += -0.5f * e * e - als - 2.3052328944f   // 0.5*ln(2pi) + 2*ln2
              + softplusf(t2) + softplusf(-t2);
    }

    // wave reduce (64) then cross-wave via LDS
    #pragma unroll
    for (int m = 1; m < 64; m <<= 1) lp += __shfl_xor(lp, m, 64);
    __shared__ float s[4];
    if ((threadIdx.x & 63) == 0) s[threadIdx.x >> 6] = lp;
    __syncthreads();
    if (threadIdx.x == 0) {
        float tot = s[0] + s[1] + s[2] + s[3];
        if ((blk & 3) == 0) tot += 14147.0828114f;  // -n_dims*ln(0.01), n_dims=3072
        atomicAdd(out + NTOK * 8 * 3 + b, tot);
    }
}

extern "C" void kernel_launch(void* const* d_in, const int* in_sizes, int n_in,
                              void* d_out, int out_size, void* d_ws, size_t ws_size,
                              hipStream_t stream) {
    const float* kv  = (const float*)d_in[0];
    const float* pos = (const float*)d_in[1];
    const float* eps = (const float*)d_in[2];
    float* out = (float*)d_out;
    float* partial = (float*)d_ws;   // needs 4*8*1024*6*4 = 768 KiB

    // zero the log_prob slots (d_out is poisoned before every launch)
    hipMemsetAsync(out + 8 * NTOK * 3, 0, 8 * sizeof(float), stream);

    actor_gemm_kernel<<<dim3(4, 16, 8), 256, 0, stream>>>(kv, pos, partial);
    actor_tail_kernel<<<dim3(32), 256, 0, stream>>>(partial, eps, out);
}

// Round 2
// 115.296 us; speedup vs baseline: 1.3718x; 1.3718x over previous
//
#include <hip/hip_runtime.h>
#include <math.h>

// B=8, N=1024, D=128.  kv[b,n,512] = [k_mu | v_mu | k_sigma | v_sigma]
// S_mu[i,j] = k_mu[i,:].v_mu[j,:] ; S_sg likewise (NT GEMM -> both MFMA
// fragments are contiguous row chunks).  Split-bf16 3-product MFMA:
// a*b ~= ah*bh + ah*bl + al*bh, rel err ~2^-17.
//
// Grid: (js 4, i-tile 16, b 8) = 512 blocks, 256 thr (4 waves), 2 blocks/CU.
// Block: i-tile 64, j-range 256 (2 chunks of 128), k staged in 4 quarters.
// Wave tile: 64i x 32j = 4(ig) x 2(jg) MFMA 16x16x32 tiles, acc persists
// over kc, epilogue folds j per jc, DPP reduces the 16 j-lanes at the end.

#define NTOK 1024
#define LPCONST 14147.0828114f   // -3072*ln(0.01)

typedef __bf16 bf16x8 __attribute__((ext_vector_type(8)));
typedef float f32x4 __attribute__((ext_vector_type(4)));
#define MFMA(a, b, c) __builtin_amdgcn_mfma_f32_16x16x32_bf16(a, b, c, 0, 0, 0)

// truncate-with-round fp32 -> (hi, lo) bf16 bit patterns
__device__ __forceinline__ void split1(float x, unsigned short& h, unsigned short& l) {
    unsigned u = __float_as_uint(x);
    unsigned hb = (u + 0x8000u) >> 16;
    float hf = __uint_as_float(hb << 16);
    unsigned lb = (__float_as_uint(x - hf) + 0x8000u) >> 16;
    h = (unsigned short)hb;
    l = (unsigned short)lb;
}

template <int CTRL>
__device__ __forceinline__ float dpp_add(float v) {
    int y = __builtin_amdgcn_update_dpp(0, __float_as_int(v), CTRL, 0xf, 0xf, true);
    return v + __int_as_float(y);
}
// sum over the 16 lanes of a DPP row (j-columns of the C tile)
__device__ __forceinline__ float red16(float v) {
    v = dpp_add<0xB1>(v);    // quad_perm(1,0,3,2)  xor1
    v = dpp_add<0x4E>(v);    // quad_perm(2,3,0,1)  xor2
    v = dpp_add<0x141>(v);   // row_half_mirror     pairs quads 0<->1, 2<->3
    v = dpp_add<0x140>(v);   // row_mirror          halves
    return v;
}

__global__ __launch_bounds__(256, 2) void actor_gemm_kernel(
    const float* __restrict__ kv, const float* __restrict__ pos,
    float* __restrict__ partial, float* __restrict__ out)
{
    // LDS: 8 arrays of bf16 tiles, k-quarter staged, row stride 40 (32 + 8 pad)
    __shared__ __align__(16) unsigned short smem[30720];   // 61440 B
    unsigned short* Ahm = smem;            // 64 x 40
    unsigned short* Alm = smem + 2560;
    unsigned short* Ahs = smem + 5120;
    unsigned short* Als = smem + 7680;
    unsigned short* Bhm = smem + 10240;    // 128 x 40
    unsigned short* Blm = smem + 15360;
    unsigned short* Bhs = smem + 20480;
    unsigned short* Bls = smem + 25600;

    const int t = threadIdx.x;
    const int w = t >> 6;        // wave 0..3
    const int lane = t & 63;
    const int q = lane >> 4;     // quad 0..3
    const int r16 = lane & 15;
    const int js = blockIdx.x;   // j-split 0..3
    const int i0 = blockIdx.y * 64;
    const int b = blockIdx.z;

    const float* kvb = kv + (size_t)b * NTOK * 512;
    const float* posb = pos + (size_t)b * NTOK * 3;

    float am[4][4][3] = {};   // [ig][reg][c] action-mean accumulators
    float al[4][4][3] = {};   // log-std side

    for (int jc = 0; jc < 2; ++jc) {
        const int jb = js * 256 + jc * 128;
        f32x4 accm[4][2], accs[4][2];
        #pragma unroll
        for (int ig = 0; ig < 4; ++ig)
            #pragma unroll
            for (int jg = 0; jg < 2; ++jg) {
                accm[ig][jg] = (f32x4){0.f, 0.f, 0.f, 0.f};
                accs[ig][jg] = (f32x4){0.f, 0.f, 0.f, 0.f};
            }

        for (int kc = 0; kc < 4; ++kc) {
            __syncthreads();
            // ---- stage A quarter: 64 rows x 32 k, k_mu & k_sigma ----
            #pragma unroll
            for (int rep = 0; rep < 2; ++rep) {
                const int e = t + rep * 256;         // float4 units, 0..511
                const int row = e >> 3;              // 0..63
                const int k4 = (e & 7) << 2;         // 0..28
                const float* gp = kvb + (size_t)(i0 + row) * 512 + kc * 32 + k4;
                const float4 vm = *(const float4*)gp;
                const float4 vs = *(const float4*)(gp + 256);
                ushort4 h, l;
                split1(vm.x, h.x, l.x); split1(vm.y, h.y, l.y);
                split1(vm.z, h.z, l.z); split1(vm.w, h.w, l.w);
                *(ushort4*)&Ahm[row * 40 + k4] = h;
                *(ushort4*)&Alm[row * 40 + k4] = l;
                split1(vs.x, h.x, l.x); split1(vs.y, h.y, l.y);
                split1(vs.z, h.z, l.z); split1(vs.w, h.w, l.w);
                *(ushort4*)&Ahs[row * 40 + k4] = h;
                *(ushort4*)&Als[row * 40 + k4] = l;
            }
            // ---- stage B chunk: 128 rows x 32 k, v_mu & v_sigma ----
            #pragma unroll
            for (int rep = 0; rep < 4; ++rep) {
                const int e = t + rep * 256;         // 0..1023
                const int row = e >> 3;              // 0..127
                const int k4 = (e & 7) << 2;
                const float* gp = kvb + (size_t)(jb + row) * 512 + 128 + kc * 32 + k4;
                const float4 vm = *(const float4*)gp;
                const float4 vs = *(const float4*)(gp + 256);
                ushort4 h, l;
                split1(vm.x, h.x, l.x); split1(vm.y, h.y, l.y);
                split1(vm.z, h.z, l.z); split1(vm.w, h.w, l.w);
                *(ushort4*)&Bhm[row * 40 + k4] = h;
                *(ushort4*)&Blm[row * 40 + k4] = l;
                split1(vs.x, h.x, l.x); split1(vs.y, h.y, l.y);
                split1(vs.z, h.z, l.z); split1(vs.w, h.w, l.w);
                *(ushort4*)&Bhs[row * 40 + k4] = h;
                *(ushort4*)&Bls[row * 40 + k4] = l;
            }
            __syncthreads();

            // ---- fragments + MFMA ----
            bf16x8 bh_m[2], bl_m[2], bh_s[2], bl_s[2];
            #pragma unroll
            for (int jg = 0; jg < 2; ++jg) {
                const int off = (w * 32 + jg * 16 + r16) * 40 + q * 8;
                bh_m[jg] = *(const bf16x8*)&Bhm[off];
                bl_m[jg] = *(const bf16x8*)&Blm[off];
                bh_s[jg] = *(const bf16x8*)&Bhs[off];
                bl_s[jg] = *(const bf16x8*)&Bls[off];
            }
            #pragma unroll
            for (int ig = 0; ig < 4; ++ig) {
                const int aoff = (ig * 16 + r16) * 40 + q * 8;
                const bf16x8 ah_m = *(const bf16x8*)&Ahm[aoff];
                const bf16x8 al_m = *(const bf16x8*)&Alm[aoff];
                const bf16x8 ah_s = *(const bf16x8*)&Ahs[aoff];
                const bf16x8 al_s = *(const bf16x8*)&Als[aoff];
                #pragma unroll
                for (int jg = 0; jg < 2; ++jg) {
                    accm[ig][jg] = MFMA(ah_m, bh_m[jg], accm[ig][jg]);
                    accm[ig][jg] = MFMA(ah_m, bl_m[jg], accm[ig][jg]);
                    accm[ig][jg] = MFMA(al_m, bh_m[jg], accm[ig][jg]);
                    accs[ig][jg] = MFMA(ah_s, bh_s[jg], accs[ig][jg]);
                    accs[ig][jg] = MFMA(ah_s, bl_s[jg], accs[ig][jg]);
                    accs[ig][jg] = MFMA(al_s, bh_s[jg], accs[ig][jg]);
                }
            }
        }

        // ---- geometric epilogue for this j-chunk ----
        float pj[2][3];
        #pragma unroll
        for (int jg = 0; jg < 2; ++jg) {
            const int j = jb + w * 32 + jg * 16 + r16;
            pj[jg][0] = posb[j * 3 + 0];
            pj[jg][1] = posb[j * 3 + 1];
            pj[jg][2] = posb[j * 3 + 2];
        }
        #pragma unroll
        for (int ig = 0; ig < 4; ++ig)
            #pragma unroll
            for (int reg = 0; reg < 4; ++reg) {
                const int i = i0 + ig * 16 + q * 4 + reg;
                const float pix = posb[i * 3 + 0];
                const float piy = posb[i * 3 + 1];
                const float piz = posb[i * 3 + 2];
                #pragma unroll
                for (int jg = 0; jg < 2; ++jg) {
                    const float dx = pix - pj[jg][0];
                    const float dy = piy - pj[jg][1];
                    const float dz = piz - pj[jg][2];
                    const float d2 = dx * dx + dy * dy + dz * dz;
                    const float inv = d2 > 0.f ? rsqrtf(d2) : 0.f;
                    const float wm = accm[ig][jg][reg] * inv;
                    const float ws = accs[ig][jg][reg] * inv;
                    am[ig][reg][0] = fmaf(dx, wm, am[ig][reg][0]);
                    am[ig][reg][1] = fmaf(dy, wm, am[ig][reg][1]);
                    am[ig][reg][2] = fmaf(dz, wm, am[ig][reg][2]);
                    al[ig][reg][0] = fmaf(dx, ws, al[ig][reg][0]);
                    al[ig][reg][1] = fmaf(dy, ws, al[ig][reg][1]);
                    al[ig][reg][2] = fmaf(dz, ws, al[ig][reg][2]);
                }
            }
    }

    // ---- reduce the 16 j-lanes (DPP, VALU pipe) ----
    #pragma unroll
    for (int ig = 0; ig < 4; ++ig)
        #pragma unroll
        for (int reg = 0; reg < 4; ++reg)
            #pragma unroll
            for (int c = 0; c < 3; ++c) {
                am[ig][reg][c] = red16(am[ig][reg][c]);
                al[ig][reg][c] = red16(al[ig][reg][c]);
            }

    // ---- cross-wave combine via LDS (alias A region; all reads done) ----
    __syncthreads();
    float* wacc = (float*)smem;   // 4 waves x 64 rows x 6
    if (r16 == 0) {
        #pragma unroll
        for (int ig = 0; ig < 4; ++ig)
            #pragma unroll
            for (int reg = 0; reg < 4; ++reg) {
                const int row = ig * 16 + q * 4 + reg;
                float* p = wacc + (w * 64 + row) * 6;
                p[0] = am[ig][reg][0]; p[1] = am[ig][reg][1]; p[2] = am[ig][reg][2];
                p[3] = al[ig][reg][0]; p[4] = al[ig][reg][1]; p[5] = al[ig][reg][2];
            }
    }
    __syncthreads();
    for (int u = t; u < 384; u += 256) {
        const int row = u / 6, c = u - row * 6;
        const float v = wacc[row * 6 + c] + wacc[(64 + row) * 6 + c] +
                        wacc[(128 + row) * 6 + c] + wacc[(192 + row) * 6 + c];
        partial[((size_t)((js * 8 + b) * NTOK) + i0 + row) * 6 + c] = v;
    }
    if (js == 0 && blockIdx.y == 0 && t == 0) out[8 * NTOK * 3 + b] = LPCONST;
}

__device__ __forceinline__ float softplusf(float z) {
    return z > 20.f ? z : log1pf(expf(z));
}

__global__ __launch_bounds__(256) void actor_tail_kernel(
    const float* __restrict__ partial, const float* __restrict__ eps,
    float* __restrict__ out)
{
    const int blk = blockIdx.x;            // 0..31
    const int b = blk >> 2;
    const int i = (blk & 3) * 256 + threadIdx.x;
    const int gi = b * NTOK + i;

    float am[3] = {}, al[3] = {};
    #pragma unroll
    for (int js = 0; js < 4; ++js) {
        const float* p = partial + (((size_t)js * 8 + b) * NTOK + i) * 6;
        am[0] += p[0]; am[1] += p[1]; am[2] += p[2];
        al[0] += p[3]; al[1] += p[4]; al[2] += p[5];
    }

    float lp = 0.f;
    #pragma unroll
    for (int c = 0; c < 3; ++c) {
        const float als = fminf(fmaxf(al[c], -20.f), 2.f);
        const float sd = expf(als);
        const float e = eps[gi * 3 + c];
        const float pre = fmaf(sd, e, am[c]);
        out[gi * 3 + c] = tanhf(pre) * 0.01f;
        const float t2 = 2.f * pre;
        lp += -0.5f * e * e - als - 2.3052328944f + softplusf(t2) + softplusf(-t2);
    }

    #pragma unroll
    for (int m = 1; m < 64; m <<= 1) lp += __shfl_xor(lp, m, 64);
    __shared__ float s[4];
    if ((threadIdx.x & 63) == 0) s[threadIdx.x >> 6] = lp;
    __syncthreads();
    if (threadIdx.x == 0)
        atomicAdd(out + NTOK * 8 * 3 + b, s[0] + s[1] + s[2] + s[3]);
}

extern "C" void kernel_launch(void* const* d_in, const int* in_sizes, int n_in,
                              void* d_out, int out_size, void* d_ws, size_t ws_size,
                              hipStream_t stream) {
    const float* kv = (const float*)d_in[0];
    const float* pos = (const float*)d_in[1];
    const float* eps = (const float*)d_in[2];
    float* out = (float*)d_out;
    float* partial = (float*)d_ws;   // 4*8*1024*6*4 = 768 KiB

    actor_gemm_kernel<<<dim3(4, 16, 8), 256, 0, stream>>>(kv, pos, partial, out);
    actor_tail_kernel<<<dim3(32), 256, 0, stream>>>(partial, eps, out);
}

// Round 3
// 107.076 us; speedup vs baseline: 1.4771x; 1.0768x over previous
//
#include <hip/hip_runtime.h>
#include <math.h>

// B=8, N=1024, D=128.  kv[b,n,512] = [k_mu | v_mu | k_sigma | v_sigma]
// 3-kernel plan:
//  1) prepass: split fp32 -> (hi,lo) bf16 and store in MFMA-fragment order:
//     frag[side][b][tile16][kc][arr][1KB chunk], chunk = 64 lanes x 16B,
//     lane = q*16 + r16 -> row tile*16+r16, k = kc*32 + q*8 .. +7.
//     side 0 = K (k_mu col 0, k_sigma col 256); side 1 = V (cols 128/384).
//     arr: 0=hi_mu 1=lo_mu 2=hi_sg 3=lo_sg.
//  2) gemm: no LDS staging, no barriers in K-loop. Each lane global-loads its
//     fragments (coalesced 1KB/wave dwordx4) and runs 3-product split-bf16
//     MFMA 16x16x32. Block = 4 waves = 64i x 128j, js=8 grid -> 1024 blocks.
//     Geometric epilogue folds S into per-i action sums, DPP-reduces the 16
//     j-lanes, cross-wave combine via 6KB LDS, writes partial[js][b][i][6].
//  3) tail: 128 blocks x 64 thr; sums 8 js partials, tanh-normal math,
//     per-wave log_prob reduce + atomicAdd.

#define NTOK 1024
#define LPCONST 14147.0828114f   // -3072*ln(0.01)

typedef __bf16 bf16x8 __attribute__((ext_vector_type(8)));
typedef float f32x4 __attribute__((ext_vector_type(4)));
#define MFMA(a, b, c) __builtin_amdgcn_mfma_f32_16x16x32_bf16(a, b, c, 0, 0, 0)

__device__ __forceinline__ void split1(float x, unsigned short& h, unsigned short& l) {
    unsigned u = __float_as_uint(x);
    unsigned hb = (u + 0x8000u) >> 16;
    float hf = __uint_as_float(hb << 16);
    unsigned lb = (__float_as_uint(x - hf) + 0x8000u) >> 16;
    h = (unsigned short)hb;
    l = (unsigned short)lb;
}

template <int CTRL>
__device__ __forceinline__ float dpp_add(float v) {
    int y = __builtin_amdgcn_update_dpp(0, __float_as_int(v), CTRL, 0xf, 0xf, true);
    return v + __int_as_float(y);
}
__device__ __forceinline__ float red16(float v) {
    v = dpp_add<0xB1>(v);    // xor1 within quad
    v = dpp_add<0x4E>(v);    // xor2 within quad
    v = dpp_add<0x141>(v);   // row_half_mirror
    v = dpp_add<0x140>(v);   // row_mirror
    return v;
}

// ---------------- prepass ----------------
__global__ __launch_bounds__(256) void prepass_kernel(
    const float* __restrict__ kv, unsigned short* __restrict__ frag)
{
    const int t = blockIdx.x * 256 + threadIdx.x;   // 0..262143
    const int lane = t & 63;
    const int kc   = (t >> 6) & 3;
    const int tile = (t >> 8) & 63;
    const int b    = (t >> 14) & 7;
    const int side = t >> 17;

    const int row = tile * 16 + (lane & 15);
    const int kof = kc * 32 + (lane >> 4) * 8;
    const float* gp = kv + ((size_t)b * NTOK + row) * 512 + side * 128 + kof;
    const float4 m0 = *(const float4*)gp;
    const float4 m1 = *(const float4*)(gp + 4);
    const float4 s0 = *(const float4*)(gp + 256);
    const float4 s1 = *(const float4*)(gp + 260);

    unsigned short* cp = frag + (size_t)side * 4194304 +
                         ((size_t)(((b * 64 + tile) * 4 + kc) * 4) << 9) + lane * 8;
    ushort4 h0, l0, h1, l1;
    split1(m0.x, h0.x, l0.x); split1(m0.y, h0.y, l0.y);
    split1(m0.z, h0.z, l0.z); split1(m0.w, h0.w, l0.w);
    split1(m1.x, h1.x, l1.x); split1(m1.y, h1.y, l1.y);
    split1(m1.z, h1.z, l1.z); split1(m1.w, h1.w, l1.w);
    *(ushort4*)(cp +   0) = h0; *(ushort4*)(cp +   4) = h1;   // arr0 hi_mu
    *(ushort4*)(cp + 512) = l0; *(ushort4*)(cp + 516) = l1;   // arr1 lo_mu
    split1(s0.x, h0.x, l0.x); split1(s0.y, h0.y, l0.y);
    split1(s0.z, h0.z, l0.z); split1(s0.w, h0.w, l0.w);
    split1(s1.x, h1.x, l1.x); split1(s1.y, h1.y, l1.y);
    split1(s1.z, h1.z, l1.z); split1(s1.w, h1.w, l1.w);
    *(ushort4*)(cp + 1024) = h0; *(ushort4*)(cp + 1028) = h1; // arr2 hi_sg
    *(ushort4*)(cp + 1536) = l0; *(ushort4*)(cp + 1540) = l1; // arr3 lo_sg
}

// ---------------- gemm ----------------
__global__ __launch_bounds__(256) void actor_gemm_kernel(
    const unsigned short* __restrict__ frag, const float* __restrict__ pos,
    float* __restrict__ partial, float* __restrict__ out)
{
    const int t = threadIdx.x;
    const int w = t >> 6;
    const int lane = t & 63;
    const int q = lane >> 4;
    const int r16 = lane & 15;
    const int js = blockIdx.x;       // 0..7
    const int itb = blockIdx.y;      // 0..15
    const int b = blockIdx.z;
    const int i0 = itb * 64;
    const int jb = js * 128;

    const unsigned short* fragA = frag;
    const unsigned short* fragB = frag + 4194304;
    const float* posb = pos + (size_t)b * NTOK * 3;

    f32x4 accm[4][2], accs[4][2];
    #pragma unroll
    for (int ig = 0; ig < 4; ++ig)
        #pragma unroll
        for (int jg = 0; jg < 2; ++jg) {
            accm[ig][jg] = (f32x4){0.f, 0.f, 0.f, 0.f};
            accs[ig][jg] = (f32x4){0.f, 0.f, 0.f, 0.f};
        }

    const int atile0 = b * 64 + itb * 4;            // +ig
    const int btile0 = b * 64 + js * 8 + w * 2;     // +jg
    const int lofs = lane * 8;

    #pragma unroll
    for (int kc = 0; kc < 4; ++kc) {
        bf16x8 Bhm[2], Blm[2], Bhs[2], Bls[2];
        #pragma unroll
        for (int jg = 0; jg < 2; ++jg) {
            const unsigned short* bp =
                fragB + (((size_t)(btile0 + jg) * 16 + kc * 4) << 9) + lofs;
            Bhm[jg] = *(const bf16x8*)(bp);
            Blm[jg] = *(const bf16x8*)(bp + 512);
            Bhs[jg] = *(const bf16x8*)(bp + 1024);
            Bls[jg] = *(const bf16x8*)(bp + 1536);
        }
        #pragma unroll
        for (int ig = 0; ig < 4; ++ig) {
            const unsigned short* ap =
                fragA + (((size_t)(atile0 + ig) * 16 + kc * 4) << 9) + lofs;
            const bf16x8 Ahm = *(const bf16x8*)(ap);
            const bf16x8 Alm = *(const bf16x8*)(ap + 512);
            const bf16x8 Ahs = *(const bf16x8*)(ap + 1024);
            const bf16x8 Als = *(const bf16x8*)(ap + 1536);
            #pragma unroll
            for (int jg = 0; jg < 2; ++jg) {
                accm[ig][jg] = MFMA(Ahm, Bhm[jg], accm[ig][jg]);
                accm[ig][jg] = MFMA(Ahm, Blm[jg], accm[ig][jg]);
                accm[ig][jg] = MFMA(Alm, Bhm[jg], accm[ig][jg]);
                accs[ig][jg] = MFMA(Ahs, Bhs[jg], accs[ig][jg]);
                accs[ig][jg] = MFMA(Ahs, Bls[jg], accs[ig][jg]);
                accs[ig][jg] = MFMA(Als, Bhs[jg], accs[ig][jg]);
            }
        }
    }

    // ---- geometric epilogue ----
    float am[4][4][3] = {};
    float al[4][4][3] = {};
    float pj[2][3];
    #pragma unroll
    for (int jg = 0; jg < 2; ++jg) {
        const int j = jb + w * 32 + jg * 16 + r16;
        pj[jg][0] = posb[j * 3 + 0];
        pj[jg][1] = posb[j * 3 + 1];
        pj[jg][2] = posb[j * 3 + 2];
    }
    #pragma unroll
    for (int ig = 0; ig < 4; ++ig)
        #pragma unroll
        for (int reg = 0; reg < 4; ++reg) {
            const int i = i0 + ig * 16 + q * 4 + reg;
            const float pix = posb[i * 3 + 0];
            const float piy = posb[i * 3 + 1];
            const float piz = posb[i * 3 + 2];
            #pragma unroll
            for (int jg = 0; jg < 2; ++jg) {
                const float dx = pix - pj[jg][0];
                const float dy = piy - pj[jg][1];
                const float dz = piz - pj[jg][2];
                const float d2 = dx * dx + dy * dy + dz * dz;
                const float inv = d2 > 0.f ? rsqrtf(d2) : 0.f;
                const float wm = accm[ig][jg][reg] * inv;
                const float ws = accs[ig][jg][reg] * inv;
                am[ig][reg][0] = fmaf(dx, wm, am[ig][reg][0]);
                am[ig][reg][1] = fmaf(dy, wm, am[ig][reg][1]);
                am[ig][reg][2] = fmaf(dz, wm, am[ig][reg][2]);
                al[ig][reg][0] = fmaf(dx, ws, al[ig][reg][0]);
                al[ig][reg][1] = fmaf(dy, ws, al[ig][reg][1]);
                al[ig][reg][2] = fmaf(dz, ws, al[ig][reg][2]);
            }
        }

    // ---- DPP-reduce the 16 j-lanes ----
    #pragma unroll
    for (int ig = 0; ig < 4; ++ig)
        #pragma unroll
        for (int reg = 0; reg < 4; ++reg)
            #pragma unroll
            for (int c = 0; c < 3; ++c) {
                am[ig][reg][c] = red16(am[ig][reg][c]);
                al[ig][reg][c] = red16(al[ig][reg][c]);
            }

    // ---- cross-wave combine via LDS ----
    __shared__ float wacc[4 * 64 * 6];
    if (r16 == 0) {
        #pragma unroll
        for (int ig = 0; ig < 4; ++ig)
            #pragma unroll
            for (int reg = 0; reg < 4; ++reg) {
                const int row = ig * 16 + q * 4 + reg;
                float* p = wacc + (w * 64 + row) * 6;
                p[0] = am[ig][reg][0]; p[1] = am[ig][reg][1]; p[2] = am[ig][reg][2];
                p[3] = al[ig][reg][0]; p[4] = al[ig][reg][1]; p[5] = al[ig][reg][2];
            }
    }
    __syncthreads();
    for (int u = t; u < 384; u += 256) {
        const int row = u / 6, c = u - row * 6;
        const float v = wacc[row * 6 + c] + wacc[(64 + row) * 6 + c] +
                        wacc[(128 + row) * 6 + c] + wacc[(192 + row) * 6 + c];
        partial[((size_t)((js * 8 + b) * NTOK) + i0 + row) * 6 + c] = v;
    }
    if (js == 0 && itb == 0 && t == 0) out[8 * NTOK * 3 + b] = LPCONST;
}

// ---------------- tail ----------------
__device__ __forceinline__ float softplusf(float z) {
    return z > 20.f ? z : log1pf(expf(z));
}

__global__ __launch_bounds__(64) void actor_tail_kernel(
    const float* __restrict__ partial, const float* __restrict__ eps,
    float* __restrict__ out)
{
    const int b = blockIdx.x >> 4;
    const int i = (blockIdx.x & 15) * 64 + threadIdx.x;
    const int gi = b * NTOK + i;

    float am[3] = {}, al[3] = {};
    #pragma unroll
    for (int js = 0; js < 8; ++js) {
        const float* p = partial + (((size_t)js * 8 + b) * NTOK + i) * 6;
        const float2 v0 = *(const float2*)(p);
        const float2 v1 = *(const float2*)(p + 2);
        const float2 v2 = *(const float2*)(p + 4);
        am[0] += v0.x; am[1] += v0.y; am[2] += v1.x;
        al[0] += v1.y; al[1] += v2.x; al[2] += v2.y;
    }

    float lp = 0.f;
    #pragma unroll
    for (int c = 0; c < 3; ++c) {
        const float als = fminf(fmaxf(al[c], -20.f), 2.f);
        const float sd = expf(als);
        const float e = eps[gi * 3 + c];
        const float pre = fmaf(sd, e, am[c]);
        out[gi * 3 + c] = tanhf(pre) * 0.01f;
        const float t2 = 2.f * pre;
        lp += -0.5f * e * e - als - 2.3052328944f + softplusf(t2) + softplusf(-t2);
    }

    #pragma unroll
    for (int m = 1; m < 64; m <<= 1) lp += __shfl_xor(lp, m, 64);
    if (threadIdx.x == 0) atomicAdd(out + NTOK * 8 * 3 + b, lp);
}

extern "C" void kernel_launch(void* const* d_in, const int* in_sizes, int n_in,
                              void* d_out, int out_size, void* d_ws, size_t ws_size,
                              hipStream_t stream) {
    const float* kv = (const float*)d_in[0];
    const float* pos = (const float*)d_in[1];
    const float* eps = (const float*)d_in[2];
    float* out = (float*)d_out;
    float* partial = (float*)d_ws;                                  // 1.5 MiB
    unsigned short* frag = (unsigned short*)((char*)d_ws + (2 << 20)); // 16 MiB

    prepass_kernel<<<dim3(1024), 256, 0, stream>>>(kv, frag);
    actor_gemm_kernel<<<dim3(8, 16, 8), 256, 0, stream>>>(frag, pos, partial, out);
    actor_tail_kernel<<<dim3(128), 64, 0, stream>>>(partial, eps, out);
}